// Round 5
// baseline (742.391 us; speedup 1.0000x reference)
//
#include <hip/hip_runtime.h>
#include <hip/hip_bf16.h>

// FP4 fake-quant MLP via MX-FP4 MFMA, 256x256 8-phase schedule (T2+T3+T4+T5).
// Quantized values are exactly the e2m1 grid {0,.5,1,1.5,2,3,4,6} * scale:
// pack 4-bit codes, run mfma_scale_f32_32x32x64_f8f6f4 with unit block scales,
// apply per-tensor scale_a*scale_b in the f32 epilogue.

typedef float f32x16 __attribute__((ext_vector_type(16)));
typedef int   i32x4  __attribute__((ext_vector_type(4)));
typedef int   i32x8  __attribute__((ext_vector_type(8)));

#define AS1 __attribute__((address_space(1)))
#define AS3 __attribute__((address_space(3)))

__device__ __forceinline__ void wg_barrier() {
    asm volatile("" ::: "memory");
    __builtin_amdgcn_s_barrier();
    asm volatile("" ::: "memory");
}

__device__ __forceinline__ float scale_from_amax_bits(unsigned bits) {
    return fmaxf(__uint_as_float(bits) / 6.0f, 1e-12f);
}

// FP4 e2m1 code: idx 0..7 over grid {0,.5,1,1.5,2,3,4,6}, sign in bit 3.
// Compare chain == np.searchsorted(mids, xs, side='left') (ties -> lower mag).
__device__ __forceinline__ unsigned q4(float v, float inv_scale) {
    float xs = fabsf(v) * inv_scale;
    unsigned idx = 0;
    idx += (xs > 0.25f);
    idx += (xs > 0.75f);
    idx += (xs > 1.25f);
    idx += (xs > 1.75f);
    idx += (xs > 2.5f);
    idx += (xs > 3.5f);
    idx += (xs > 5.0f);
    return idx | ((v < 0.0f) ? 8u : 0u);
}

// ---------- tiny utility kernels ----------
__global__ void zero4_kernel(unsigned* p) {
    if (threadIdx.x < 4) p[threadIdx.x] = 0u;
}

__global__ void sentinel_kernel(float* out, long long n) {
    long long i = (long long)blockIdx.x * blockDim.x + threadIdx.x;
    long long stride = (long long)gridDim.x * blockDim.x;
    for (; i < n; i += stride) out[i] = 1e30f;
}

// ---------- absmax reduction (n % 4 == 0) ----------
__global__ void absmax_kernel(const float* __restrict__ in, long long n,
                              unsigned* __restrict__ out) {
    long long i = ((long long)blockIdx.x * blockDim.x + threadIdx.x) * 4;
    long long stride = (long long)gridDim.x * blockDim.x * 4;
    float m = 0.0f;
    for (; i < n; i += stride) {
        float4 v = *(const float4*)&in[i];
        m = fmaxf(m, fmaxf(fmaxf(fabsf(v.x), fabsf(v.y)),
                           fmaxf(fabsf(v.z), fabsf(v.w))));
    }
    #pragma unroll
    for (int off = 32; off > 0; off >>= 1)
        m = fmaxf(m, __shfl_xor(m, off));
    __shared__ float smax[4];
    int lane = threadIdx.x & 63, w = threadIdx.x >> 6;
    if (lane == 0) smax[w] = m;
    __syncthreads();
    if (threadIdx.x == 0) {
        m = fmaxf(fmaxf(smax[0], smax[1]), fmaxf(smax[2], smax[3]));
        atomicMax(out, __float_as_uint(m));  // valid: all values >= 0
    }
}

// ---------- quantize f32 -> packed fp4 (n % 8 == 0), k-major nibbles ----------
__global__ void quant_pack_kernel(const float* __restrict__ in, long long n,
                                  const unsigned* __restrict__ amax,
                                  unsigned* __restrict__ out) {
    float inv = 1.0f / scale_from_amax_bits(*amax);
    long long i = ((long long)blockIdx.x * blockDim.x + threadIdx.x) * 8;
    long long stride = (long long)gridDim.x * blockDim.x * 8;
    for (; i < n; i += stride) {
        float4 a = *(const float4*)&in[i];
        float4 b = *(const float4*)&in[i + 4];
        unsigned u = q4(a.x, inv)        | (q4(a.y, inv) << 4)
                   | (q4(a.z, inv) << 8) | (q4(a.w, inv) << 12)
                   | (q4(b.x, inv) << 16)| (q4(b.y, inv) << 20)
                   | (q4(b.z, inv) << 24)| (q4(b.w, inv) << 28);
        out[i >> 3] = u;
    }
}

// ---------- quantize + transpose + pack: in [R][C] f32 -> out [C][R/2] bytes --
__global__ void quant_transpose_pack_kernel(const float* __restrict__ in, int R, int C,
                                            const unsigned* __restrict__ amax,
                                            unsigned char* __restrict__ out) {
    __shared__ float tile[64][65];
    float inv = 1.0f / scale_from_amax_bits(*amax);
    int t = threadIdx.x;
    int CT = C >> 6;
    int tc = blockIdx.x % CT;
    int tr = blockIdx.x / CT;
    int r0 = t >> 4;            // 0..15
    int c0 = (t & 15) * 4;      // 0..60
    #pragma unroll
    for (int it = 0; it < 4; ++it) {
        int r = r0 + it * 16;
        float4 v = *(const float4*)&in[(size_t)(tr * 64 + r) * C + tc * 64 + c0];
        tile[r][c0 + 0] = v.x;
        tile[r][c0 + 1] = v.y;
        tile[r][c0 + 2] = v.z;
        tile[r][c0 + 3] = v.w;
    }
    __syncthreads();
    int c = t >> 2;             // 0..63 : output row (= input column)
    int rch = (t & 3) * 16;     // k-chunk of 16 values
    unsigned u0 = 0, u1 = 0;
    #pragma unroll
    for (int j = 0; j < 8; ++j) u0 |= q4(tile[rch + j][c], inv) << (4 * j);
    #pragma unroll
    for (int j = 0; j < 8; ++j) u1 |= q4(tile[rch + 8 + j][c], inv) << (4 * j);
    uint2 o; o.x = u0; o.y = u1;
    *(uint2*)&out[(size_t)(tc * 64 + c) * (R >> 1) + (size_t)(tr * 32) + (rch >> 1)] = o;
}

// ---------- fp4 MFMA helper ----------
__device__ __forceinline__ f32x16 mm_fp4(i32x4 a, i32x4 b, f32x16 c) {
    i32x8 a8 = {a[0], a[1], a[2], a[3], 0, 0, 0, 0};
    i32x8 b8 = {b[0], b[1], b[2], b[3], 0, 0, 0, 0};
    return __builtin_amdgcn_mfma_scale_f32_32x32x64_f8f6f4(
        a8, b8, c, 4, 4,            // cbsz=fp4, blgp=fp4
        0, 0x7f7f7f7f,              // scale_a: E8M0 1.0
        0, 0x7f7f7f7f);             // scale_b: E8M0 1.0
}

// ---------- FP4 GEMM, 256x256 tile, BK=256 fp4 (128B), 8-phase schedule ------
// Ap: [M][K/2] bytes (fp4 k-major); Bp: [N][K/2]; C: [M][N] f32.
// 512 threads = 8 waves (2M x 4N), each wave owns 128x64 of C.
// LDS 128KB: per matrix 2 dbuf x 2 halves x 128 rows x 128B, XOR chunk-swizzled
// (slot = chunk ^ (row&7)) via pre-swizzled global source (rule #21).
// Per K-tile: 4 phases {ds_read subtile; stage 1 half-tile; barrier;
// setprio(1) 8xMFMA setprio(0); [vmcnt gate at P4]; barrier}.
// Stage schedule (iter t, d=t&1, dn=1-d): P1: A[dn][1] of t+1; P2: B[dn][0];
// P3: B[dn][1]; P4: A[d][0] of t+2. Each target's last read is >=1 barrier
// earlier; vmcnt(2) at P4 drains exactly tile t+1's 4 half-tiles.
template <int RELU, int FUSE_AMAX>
__global__ __launch_bounds__(512, 2)
void gemm_fp4_8ph(const unsigned char* __restrict__ Ap,
                  const unsigned char* __restrict__ Bp,
                  float* __restrict__ C, const float* __restrict__ bias,
                  const unsigned* __restrict__ amaxA,
                  const unsigned* __restrict__ amaxB,
                  unsigned* __restrict__ amaxOut,
                  int M, int N, int K) {
    __shared__ alignas(16) unsigned char As[65536];
    __shared__ alignas(16) unsigned char Bs[65536];
    __shared__ float smax[8];

    // bijective XCD swizzle (gridDim.x % 8 == 0 by construction)
    int nwg = gridDim.x;
    int cpx = nwg >> 3;
    int wg = (blockIdx.x & 7) * cpx + (blockIdx.x >> 3);
    int MT = M >> 8;
    int tm = wg % MT;
    int tn = wg / MT;

    int tid = threadIdx.x;
    int lane = tid & 63;
    int wid = tid >> 6;            // 0..7
    int wr = wid >> 2;             // 0..1 : M half
    int wc = wid & 3;              // 0..3 : N quarter

    size_t Kb = (size_t)(K >> 1);

    // staging: one call = 512 lanes x 16B = 8KB = 64 rows x 128B.
    // lane covers row (tid>>3), chunk (tid&7); source chunk pre-swizzled.
    int srow = tid >> 3;
    int scs = ((tid & 7) ^ (srow & 7)) << 4;
    const unsigned char* Ag = Ap + ((size_t)(tm * 256) + srow) * Kb + scs;
    const unsigned char* Bg = Bp + ((size_t)(tn * 256) + srow) * Kb + scs;
    char* AsB = (char*)As;
    char* BsB = (char*)Bs;
    int stageOff = wid << 10;      // wave-uniform; HW adds lane*16

#define STG_A(d, h, j, kt)                                                     \
    __builtin_amdgcn_global_load_lds(                                          \
        (const AS1 void*)(Ag + (size_t)((h) * 128 + (j) * 64) * Kb +           \
                          (size_t)(kt) * 128),                                 \
        (AS3 void*)(AsB + ((d) << 15) + ((h) << 14) + ((j) << 13) + stageOff), \
        16, 0, 0)
#define STG_B(d, h, j, kt)                                                     \
    __builtin_amdgcn_global_load_lds(                                          \
        (const AS1 void*)(Bg + (size_t)((h) * 128 + (j) * 64) * Kb +           \
                          (size_t)(kt) * 128),                                 \
        (AS3 void*)(BsB + ((d) << 15) + ((h) << 14) + ((j) << 13) + stageOff), \
        16, 0, 0)
#define STG_AH(d, h, kt) do { STG_A(d, h, 0, kt); STG_A(d, h, 1, kt); } while (0)
#define STG_BH(d, h, kt) do { STG_B(d, h, 0, kt); STG_B(d, h, 1, kt); } while (0)

    // fragment read addressing: A row (within wave half) = mi*32 + (lane&31),
    // B row = (wc&1)*64 + ni*32 + (lane&31); 16B chunk c = ks*2 + (lane>>5),
    // LDS slot = c ^ (row&7) = c ^ (lane&7).
    int l31 = lane & 31, l7 = lane & 7, kh = lane >> 5;
    const char* Ard = AsB + (wr << 14) + l31 * 128;
    const char* Brd = BsB + ((wc >> 1) << 14) + ((wc & 1) << 13) + l31 * 128;
    int so[4];
    #pragma unroll
    for (int ks = 0; ks < 4; ++ks) so[ks] = (((ks * 2 + kh) ^ l7) << 4);

    f32x16 acc[4][2] = {};

    int KT = K >> 8;               // K-tiles of 256 fp4

    // prologue: tile 0 fully + tile 1's A-half0; drain tile 0 (leave 2 in flight)
    STG_AH(0, 0, 0); STG_AH(0, 1, 0);
    STG_BH(0, 0, 0); STG_BH(0, 1, 0);
    STG_AH(1, 0, 1);
    asm volatile("s_waitcnt vmcnt(2)" ::: "memory");
    wg_barrier();

    for (int t = 0; t < KT; ++t) {
        int d = t & 1, dn = d ^ 1;
        int dOff = d << 15;
        const char* Aq = Ard + dOff;
        const char* Bq = Brd + dOff;
        i32x4 a0[2][4], a1[2][4], b0[4], b1[4];

        // ---- P1: read A mi0-1 + B ni0; stage A[dn][1] of tile t+1
        #pragma unroll
        for (int mi = 0; mi < 2; ++mi)
            #pragma unroll
            for (int ks = 0; ks < 4; ++ks)
                a0[mi][ks] = *(const i32x4*)(Aq + mi * 4096 + so[ks]);
        #pragma unroll
        for (int ks = 0; ks < 4; ++ks)
            b0[ks] = *(const i32x4*)(Bq + so[ks]);
        if (t + 1 < KT) STG_AH(dn, 1, t + 1);
        wg_barrier();
        __builtin_amdgcn_s_setprio(1);
        __builtin_amdgcn_sched_barrier(0);
        #pragma unroll
        for (int mi = 0; mi < 2; ++mi)
            #pragma unroll
            for (int ks = 0; ks < 4; ++ks)
                acc[mi][0] = mm_fp4(a0[mi][ks], b0[ks], acc[mi][0]);
        __builtin_amdgcn_sched_barrier(0);
        __builtin_amdgcn_s_setprio(0);
        wg_barrier();

        // ---- P2: read B ni1; stage B[dn][0] of t+1
        #pragma unroll
        for (int ks = 0; ks < 4; ++ks)
            b1[ks] = *(const i32x4*)(Bq + 4096 + so[ks]);
        if (t + 1 < KT) STG_BH(dn, 0, t + 1);
        wg_barrier();
        __builtin_amdgcn_s_setprio(1);
        __builtin_amdgcn_sched_barrier(0);
        #pragma unroll
        for (int mi = 0; mi < 2; ++mi)
            #pragma unroll
            for (int ks = 0; ks < 4; ++ks)
                acc[mi][1] = mm_fp4(a0[mi][ks], b1[ks], acc[mi][1]);
        __builtin_amdgcn_sched_barrier(0);
        __builtin_amdgcn_s_setprio(0);
        wg_barrier();

        // ---- P3: read A mi2-3; stage B[dn][1] of t+1
        #pragma unroll
        for (int mi = 0; mi < 2; ++mi)
            #pragma unroll
            for (int ks = 0; ks < 4; ++ks)
                a1[mi][ks] = *(const i32x4*)(Aq + (2 + mi) * 4096 + so[ks]);
        if (t + 1 < KT) STG_BH(dn, 1, t + 1);
        wg_barrier();
        __builtin_amdgcn_s_setprio(1);
        __builtin_amdgcn_sched_barrier(0);
        #pragma unroll
        for (int mi = 0; mi < 2; ++mi)
            #pragma unroll
            for (int ks = 0; ks < 4; ++ks)
                acc[2 + mi][1] = mm_fp4(a1[mi][ks], b1[ks], acc[2 + mi][1]);
        __builtin_amdgcn_sched_barrier(0);
        __builtin_amdgcn_s_setprio(0);
        wg_barrier();

        // ---- P4: no reads (reuse a1, b0); stage A[d][0] of t+2; vmcnt gate
        if (t + 2 < KT) STG_AH(d, 0, t + 2);
        wg_barrier();
        __builtin_amdgcn_s_setprio(1);
        __builtin_amdgcn_sched_barrier(0);
        #pragma unroll
        for (int mi = 0; mi < 2; ++mi)
            #pragma unroll
            for (int ks = 0; ks < 4; ++ks)
                acc[2 + mi][0] = mm_fp4(a1[mi][ks], b0[ks], acc[2 + mi][0]);
        __builtin_amdgcn_sched_barrier(0);
        __builtin_amdgcn_s_setprio(0);
        if (t + 2 < KT) { asm volatile("s_waitcnt vmcnt(2)" ::: "memory"); }
        else            { asm volatile("s_waitcnt vmcnt(0)" ::: "memory"); }
        wg_barrier();
        (void)dn;
    }

    // ---- epilogue: scale + bias + relu + store (+ fused absmax) ----
    float s = scale_from_amax_bits(*amaxA) * scale_from_amax_bits(*amaxB);
    float vmax = 0.0f;
    int colBase = tn * 256 + wc * 64 + l31;
    int rowB0 = tm * 256 + wr * 128 + (kh << 2);
    #pragma unroll
    for (int mi = 0; mi < 4; ++mi) {
        #pragma unroll
        for (int ni = 0; ni < 2; ++ni) {
            int col = colBase + ni * 32;
            float bv = bias[col];
            #pragma unroll
            for (int rg = 0; rg < 4; ++rg) {
                #pragma unroll
                for (int rr = 0; rr < 4; ++rr) {
                    float v = acc[mi][ni][rg * 4 + rr] * s + bv;
                    if (RELU) v = fmaxf(v, 0.0f);
                    if (FUSE_AMAX) vmax = fmaxf(vmax, fabsf(v));
                    C[(size_t)(rowB0 + mi * 32 + rg * 8 + rr) * N + col] = v;
                }
            }
        }
    }
    if (FUSE_AMAX) {
        #pragma unroll
        for (int off = 32; off > 0; off >>= 1)
            vmax = fmaxf(vmax, __shfl_xor(vmax, off));
        if (lane == 0) smax[wid] = vmax;
        __syncthreads();
        if (tid == 0) {
            float m = smax[0];
            #pragma unroll
            for (int i = 1; i < 8; ++i) m = fmaxf(m, smax[i]);
            atomicMax(amaxOut, __float_as_uint(m));
        }
    }
#undef STG_A
#undef STG_B
#undef STG_AH
#undef STG_BH
}

// ---------- launch ----------
extern "C" void kernel_launch(void* const* d_in, const int* in_sizes, int n_in,
                              void* d_out, int out_size, void* d_ws, size_t ws_size,
                              hipStream_t stream) {
    const float* x  = (const float*)d_in[0];
    const float* w1 = (const float*)d_in[1];
    const float* b1 = (const float*)d_in[2];
    const float* w2 = (const float*)d_in[3];
    const float* b2 = (const float*)d_in[4];
    float* out = (float*)d_out;

    const int B = 4096, DIN = 4096, DH = 16384, DOUT = 4096;

    // workspace layout (packed fp4 operands)
    const size_t off_amax = 0;                                    // 4 uints
    const size_t off_Xq   = 256;                                  // 8 MB
    const size_t off_W    = off_Xq + (size_t)B * DIN / 2;         // 32 MB
    const size_t off_h    = off_W + (size_t)DIN * DH / 2;         // 256 MB f32
    const size_t off_Hq   = off_h + (size_t)B * DH * 4;           // 32 MB
    const size_t needed   = off_Hq + (size_t)B * DH / 2;

    if (ws_size < needed) {
        sentinel_kernel<<<2048, 256, 0, stream>>>(out, (long long)out_size);
        return;
    }

    char* ws = (char*)d_ws;
    unsigned* amax = (unsigned*)(ws + off_amax);  // [0]=x [1]=w1 [2]=h [3]=w2
    unsigned char* Xq = (unsigned char*)(ws + off_Xq);
    unsigned char* Wq = (unsigned char*)(ws + off_W);
    float*         h  = (float*)(ws + off_h);
    unsigned char* Hq = (unsigned char*)(ws + off_Hq);

    zero4_kernel<<<1, 64, 0, stream>>>(amax);

    absmax_kernel<<<2048, 256, 0, stream>>>(x, (long long)B * DIN, amax + 0);
    absmax_kernel<<<2048, 256, 0, stream>>>(w1, (long long)DIN * DH, amax + 1);
    absmax_kernel<<<2048, 256, 0, stream>>>(w2, (long long)DH * DOUT, amax + 3);

    quant_pack_kernel<<<2048, 256, 0, stream>>>(x, (long long)B * DIN, amax + 0,
                                                (unsigned*)Xq);
    quant_transpose_pack_kernel<<<(DIN / 64) * (DH / 64), 256, 0, stream>>>(
        w1, DIN, DH, amax + 1, Wq);

    // h = relu(Q(x) @ Q(w1) + b1), fused absmax(h) -> amax[2]
    gemm_fp4_8ph<1, 1><<<(B / 256) * (DH / 256), 512, 0, stream>>>(
        Xq, Wq, h, b1, amax + 0, amax + 1, amax + 2, B, DH, DIN);

    quant_pack_kernel<<<2048, 256, 0, stream>>>(h, (long long)B * DH, amax + 2,
                                                (unsigned*)Hq);
    quant_transpose_pack_kernel<<<(DH / 64) * (DOUT / 64), 256, 0, stream>>>(
        w2, DH, DOUT, amax + 3, Wq);

    // out = Q(h) @ Q(w2) + b2
    gemm_fp4_8ph<0, 0><<<(B / 256) * (DOUT / 256), 512, 0, stream>>>(
        Hq, Wq, out, b2, amax + 2, amax + 3, nullptr, B, DOUT, DH);
}

// Round 6
// 741.891 us; speedup vs baseline: 1.0007x; 1.0007x over previous
//
#include <hip/hip_runtime.h>
#include <hip/hip_bf16.h>

// FP4 fake-quant MLP via MX-FP4 MFMA, 256x256 8-phase schedule (T2+T3+T4+T5).
// Quantized values are exactly the e2m1 grid {0,.5,1,1.5,2,3,4,6} * scale:
// pack 4-bit codes, run mfma_scale_f32_32x32x64_f8f6f4 with unit block scales,
// apply per-tensor scale_a*scale_b in the f32 epilogue.

typedef float f32x16 __attribute__((ext_vector_type(16)));
typedef int   i32x4  __attribute__((ext_vector_type(4)));
typedef int   i32x8  __attribute__((ext_vector_type(8)));

#define AS1 __attribute__((address_space(1)))
#define AS3 __attribute__((address_space(3)))

__device__ __forceinline__ void wg_barrier() {
    asm volatile("" ::: "memory");
    __builtin_amdgcn_s_barrier();
    asm volatile("" ::: "memory");
}

__device__ __forceinline__ float scale_from_amax_bits(unsigned bits) {
    return fmaxf(__uint_as_float(bits) / 6.0f, 1e-12f);
}

// FP4 e2m1 code: idx 0..7 over grid {0,.5,1,1.5,2,3,4,6}, sign in bit 3.
// Compare chain == np.searchsorted(mids, xs, side='left') (ties -> lower mag).
__device__ __forceinline__ unsigned q4(float v, float inv_scale) {
    float xs = fabsf(v) * inv_scale;
    unsigned idx = 0;
    idx += (xs > 0.25f);
    idx += (xs > 0.75f);
    idx += (xs > 1.25f);
    idx += (xs > 1.75f);
    idx += (xs > 2.5f);
    idx += (xs > 3.5f);
    idx += (xs > 5.0f);
    return idx | ((v < 0.0f) ? 8u : 0u);
}

// ---------- tiny utility kernels ----------
__global__ void zero4_kernel(unsigned* p) {
    if (threadIdx.x < 4) p[threadIdx.x] = 0u;
}

__global__ void sentinel_kernel(float* out, long long n) {
    long long i = (long long)blockIdx.x * blockDim.x + threadIdx.x;
    long long stride = (long long)gridDim.x * blockDim.x;
    for (; i < n; i += stride) out[i] = 1e30f;
}

// ---------- absmax reduction (n % 4 == 0) ----------
__global__ void absmax_kernel(const float* __restrict__ in, long long n,
                              unsigned* __restrict__ out) {
    long long i = ((long long)blockIdx.x * blockDim.x + threadIdx.x) * 4;
    long long stride = (long long)gridDim.x * blockDim.x * 4;
    float m = 0.0f;
    for (; i < n; i += stride) {
        float4 v = *(const float4*)&in[i];
        m = fmaxf(m, fmaxf(fmaxf(fabsf(v.x), fabsf(v.y)),
                           fmaxf(fabsf(v.z), fabsf(v.w))));
    }
    #pragma unroll
    for (int off = 32; off > 0; off >>= 1)
        m = fmaxf(m, __shfl_xor(m, off));
    __shared__ float smax[4];
    int lane = threadIdx.x & 63, w = threadIdx.x >> 6;
    if (lane == 0) smax[w] = m;
    __syncthreads();
    if (threadIdx.x == 0) {
        m = fmaxf(fmaxf(smax[0], smax[1]), fmaxf(smax[2], smax[3]));
        atomicMax(out, __float_as_uint(m));  // valid: all values >= 0
    }
}

// ---------- quantize f32 -> packed fp4 (n % 8 == 0), k-major nibbles ----------
__global__ void quant_pack_kernel(const float* __restrict__ in, long long n,
                                  const unsigned* __restrict__ amax,
                                  unsigned* __restrict__ out) {
    float inv = 1.0f / scale_from_amax_bits(*amax);
    long long i = ((long long)blockIdx.x * blockDim.x + threadIdx.x) * 8;
    long long stride = (long long)gridDim.x * blockDim.x * 8;
    for (; i < n; i += stride) {
        float4 a = *(const float4*)&in[i];
        float4 b = *(const float4*)&in[i + 4];
        unsigned u = q4(a.x, inv)        | (q4(a.y, inv) << 4)
                   | (q4(a.z, inv) << 8) | (q4(a.w, inv) << 12)
                   | (q4(b.x, inv) << 16)| (q4(b.y, inv) << 20)
                   | (q4(b.z, inv) << 24)| (q4(b.w, inv) << 28);
        out[i >> 3] = u;
    }
}

// ---------- quantize + transpose + pack: in [R][C] f32 -> out [C][R/2] bytes --
__global__ void quant_transpose_pack_kernel(const float* __restrict__ in, int R, int C,
                                            const unsigned* __restrict__ amax,
                                            unsigned char* __restrict__ out) {
    __shared__ float tile[64][65];
    float inv = 1.0f / scale_from_amax_bits(*amax);
    int t = threadIdx.x;
    int CT = C >> 6;
    int tc = blockIdx.x % CT;
    int tr = blockIdx.x / CT;
    int r0 = t >> 4;            // 0..15
    int c0 = (t & 15) * 4;      // 0..60
    #pragma unroll
    for (int it = 0; it < 4; ++it) {
        int r = r0 + it * 16;
        float4 v = *(const float4*)&in[(size_t)(tr * 64 + r) * C + tc * 64 + c0];
        tile[r][c0 + 0] = v.x;
        tile[r][c0 + 1] = v.y;
        tile[r][c0 + 2] = v.z;
        tile[r][c0 + 3] = v.w;
    }
    __syncthreads();
    int c = t >> 2;             // 0..63 : output row (= input column)
    int rch = (t & 3) * 16;     // k-chunk of 16 values
    unsigned u0 = 0, u1 = 0;
    #pragma unroll
    for (int j = 0; j < 8; ++j) u0 |= q4(tile[rch + j][c], inv) << (4 * j);
    #pragma unroll
    for (int j = 0; j < 8; ++j) u1 |= q4(tile[rch + 8 + j][c], inv) << (4 * j);
    uint2 o; o.x = u0; o.y = u1;
    *(uint2*)&out[(size_t)(tc * 64 + c) * (R >> 1) + (size_t)(tr * 32) + (rch >> 1)] = o;
}

// ---------- fp4 MFMA helper ----------
__device__ __forceinline__ f32x16 mm_fp4(i32x4 a, i32x4 b, f32x16 c) {
    i32x8 a8 = {a[0], a[1], a[2], a[3], 0, 0, 0, 0};
    i32x8 b8 = {b[0], b[1], b[2], b[3], 0, 0, 0, 0};
    return __builtin_amdgcn_mfma_scale_f32_32x32x64_f8f6f4(
        a8, b8, c, 4, 4,            // cbsz=fp4, blgp=fp4
        0, 0x7f7f7f7f,              // scale_a: E8M0 1.0
        0, 0x7f7f7f7f);             // scale_b: E8M0 1.0
}

// ---------- FP4 GEMM, 256x256 tile, BK=256 fp4 (128B), 8-phase schedule ------
// Ap: [M][K/2] bytes (fp4 k-major); Bp: [N][K/2]; C: [M][N] f32.
// 512 threads = 8 waves (2M x 4N), each wave owns 128x64 of C.
// LDS 128KB: per matrix 2 dbuf x 2 halves x 128 rows x 128B, XOR chunk-swizzled
// (slot = chunk ^ (row&7)) via pre-swizzled global source (rule #21).
// Per K-tile: 4 phases {ds_read subtile; stage 1 half-tile; barrier;
// setprio(1) 8xMFMA setprio(0); [vmcnt gate at P4]; barrier}.
// Stage schedule (iter t, d=t&1, dn=1-d): P1: A[dn][1] of t+1; P2: B[dn][0];
// P3: B[dn][1]; P4: A[d][0] of t+2. Each target's last read is >=1 barrier
// earlier; vmcnt(2) at P4 drains exactly tile t+1's 4 half-tiles.
template <int RELU, int FUSE_AMAX>
__global__ __launch_bounds__(512, 2)
void gemm_fp4_8ph(const unsigned char* __restrict__ Ap,
                  const unsigned char* __restrict__ Bp,
                  float* __restrict__ C, const float* __restrict__ bias,
                  const unsigned* __restrict__ amaxA,
                  const unsigned* __restrict__ amaxB,
                  unsigned* __restrict__ amaxOut,
                  int M, int N, int K) {
    __shared__ alignas(16) unsigned char As[65536];
    __shared__ alignas(16) unsigned char Bs[65536];
    __shared__ float smax[8];

    // bijective XCD swizzle (gridDim.x % 8 == 0 by construction)
    int nwg = gridDim.x;
    int cpx = nwg >> 3;
    int wg = (blockIdx.x & 7) * cpx + (blockIdx.x >> 3);
    int MT = M >> 8;
    int tm = wg % MT;
    int tn = wg / MT;

    int tid = threadIdx.x;
    int lane = tid & 63;
    int wid = tid >> 6;            // 0..7
    int wr = wid >> 2;             // 0..1 : M half
    int wc = wid & 3;              // 0..3 : N quarter

    size_t Kb = (size_t)(K >> 1);

    // staging: one call = 512 lanes x 16B = 8KB = 64 rows x 128B.
    // lane covers row (tid>>3), chunk (tid&7); source chunk pre-swizzled.
    int srow = tid >> 3;
    int scs = ((tid & 7) ^ (srow & 7)) << 4;
    const unsigned char* Ag = Ap + ((size_t)(tm * 256) + srow) * Kb + scs;
    const unsigned char* Bg = Bp + ((size_t)(tn * 256) + srow) * Kb + scs;
    char* AsB = (char*)As;
    char* BsB = (char*)Bs;
    int stageOff = wid << 10;      // wave-uniform; HW adds lane*16

#define STG_A(d, h, j, kt)                                                     \
    __builtin_amdgcn_global_load_lds(                                          \
        (const AS1 void*)(Ag + (size_t)((h) * 128 + (j) * 64) * Kb +           \
                          (size_t)(kt) * 128),                                 \
        (AS3 void*)(AsB + ((d) << 15) + ((h) << 14) + ((j) << 13) + stageOff), \
        16, 0, 0)
#define STG_B(d, h, j, kt)                                                     \
    __builtin_amdgcn_global_load_lds(                                          \
        (const AS1 void*)(Bg + (size_t)((h) * 128 + (j) * 64) * Kb +           \
                          (size_t)(kt) * 128),                                 \
        (AS3 void*)(BsB + ((d) << 15) + ((h) << 14) + ((j) << 13) + stageOff), \
        16, 0, 0)
#define STG_AH(d, h, kt) do { STG_A(d, h, 0, kt); STG_A(d, h, 1, kt); } while (0)
#define STG_BH(d, h, kt) do { STG_B(d, h, 0, kt); STG_B(d, h, 1, kt); } while (0)

    // fragment read addressing: A row (within wave half) = mi*32 + (lane&31),
    // B row = (wc&1)*64 + ni*32 + (lane&31); 16B chunk c = ks*2 + (lane>>5),
    // LDS slot = c ^ (row&7) = c ^ (lane&7).
    int l31 = lane & 31, l7 = lane & 7, kh = lane >> 5;
    const char* Ard = AsB + (wr << 14) + l31 * 128;
    const char* Brd = BsB + ((wc >> 1) << 14) + ((wc & 1) << 13) + l31 * 128;
    int so[4];
    #pragma unroll
    for (int ks = 0; ks < 4; ++ks) so[ks] = (((ks * 2 + kh) ^ l7) << 4);

    f32x16 acc[4][2] = {};

    int KT = K >> 8;               // K-tiles of 256 fp4

    // prologue: tile 0 fully + tile 1's A-half0; drain tile 0 (leave 2 in flight)
    STG_AH(0, 0, 0); STG_AH(0, 1, 0);
    STG_BH(0, 0, 0); STG_BH(0, 1, 0);
    STG_AH(1, 0, 1);
    asm volatile("s_waitcnt vmcnt(2)" ::: "memory");
    wg_barrier();

    for (int t = 0; t < KT; ++t) {
        int d = t & 1, dn = d ^ 1;
        int dOff = d << 15;
        const char* Aq = Ard + dOff;
        const char* Bq = Brd + dOff;
        i32x4 a0[2][4], a1[2][4], b0[4], b1[4];

        // ---- P1: read A mi0-1 + B ni0; stage A[dn][1] of tile t+1
        #pragma unroll
        for (int mi = 0; mi < 2; ++mi)
            #pragma unroll
            for (int ks = 0; ks < 4; ++ks)
                a0[mi][ks] = *(const i32x4*)(Aq + mi * 4096 + so[ks]);
        #pragma unroll
        for (int ks = 0; ks < 4; ++ks)
            b0[ks] = *(const i32x4*)(Bq + so[ks]);
        if (t + 1 < KT) STG_AH(dn, 1, t + 1);
        wg_barrier();
        __builtin_amdgcn_s_setprio(1);
        __builtin_amdgcn_sched_barrier(0);
        #pragma unroll
        for (int mi = 0; mi < 2; ++mi)
            #pragma unroll
            for (int ks = 0; ks < 4; ++ks)
                acc[mi][0] = mm_fp4(a0[mi][ks], b0[ks], acc[mi][0]);
        __builtin_amdgcn_sched_barrier(0);
        __builtin_amdgcn_s_setprio(0);
        wg_barrier();

        // ---- P2: read B ni1; stage B[dn][0] of t+1
        #pragma unroll
        for (int ks = 0; ks < 4; ++ks)
            b1[ks] = *(const i32x4*)(Bq + 4096 + so[ks]);
        if (t + 1 < KT) STG_BH(dn, 0, t + 1);
        wg_barrier();
        __builtin_amdgcn_s_setprio(1);
        __builtin_amdgcn_sched_barrier(0);
        #pragma unroll
        for (int mi = 0; mi < 2; ++mi)
            #pragma unroll
            for (int ks = 0; ks < 4; ++ks)
                acc[mi][1] = mm_fp4(a0[mi][ks], b1[ks], acc[mi][1]);
        __builtin_amdgcn_sched_barrier(0);
        __builtin_amdgcn_s_setprio(0);
        wg_barrier();

        // ---- P3: read A mi2-3; stage B[dn][1] of t+1
        #pragma unroll
        for (int mi = 0; mi < 2; ++mi)
            #pragma unroll
            for (int ks = 0; ks < 4; ++ks)
                a1[mi][ks] = *(const i32x4*)(Aq + (2 + mi) * 4096 + so[ks]);
        if (t + 1 < KT) STG_BH(dn, 1, t + 1);
        wg_barrier();
        __builtin_amdgcn_s_setprio(1);
        __builtin_amdgcn_sched_barrier(0);
        #pragma unroll
        for (int mi = 0; mi < 2; ++mi)
            #pragma unroll
            for (int ks = 0; ks < 4; ++ks)
                acc[2 + mi][1] = mm_fp4(a1[mi][ks], b1[ks], acc[2 + mi][1]);
        __builtin_amdgcn_sched_barrier(0);
        __builtin_amdgcn_s_setprio(0);
        wg_barrier();

        // ---- P4: no reads (reuse a1, b0); stage A[d][0] of t+2; vmcnt gate
        if (t + 2 < KT) STG_AH(d, 0, t + 2);
        wg_barrier();
        __builtin_amdgcn_s_setprio(1);
        __builtin_amdgcn_sched_barrier(0);
        #pragma unroll
        for (int mi = 0; mi < 2; ++mi)
            #pragma unroll
            for (int ks = 0; ks < 4; ++ks)
                acc[2 + mi][0] = mm_fp4(a1[mi][ks], b0[ks], acc[2 + mi][0]);
        __builtin_amdgcn_sched_barrier(0);
        __builtin_amdgcn_s_setprio(0);
        if (t + 2 < KT) { asm volatile("s_waitcnt vmcnt(2)" ::: "memory"); }
        else            { asm volatile("s_waitcnt vmcnt(0)" ::: "memory"); }
        wg_barrier();
        (void)dn;
    }

    // ---- epilogue: scale + bias + relu + store (+ fused absmax) ----
    float s = scale_from_amax_bits(*amaxA) * scale_from_amax_bits(*amaxB);
    float vmax = 0.0f;
    int colBase = tn * 256 + wc * 64 + l31;
    int rowB0 = tm * 256 + wr * 128 + (kh << 2);
    #pragma unroll
    for (int mi = 0; mi < 4; ++mi) {
        #pragma unroll
        for (int ni = 0; ni < 2; ++ni) {
            int col = colBase + ni * 32;
            float bv = bias[col];
            #pragma unroll
            for (int rg = 0; rg < 4; ++rg) {
                #pragma unroll
                for (int rr = 0; rr < 4; ++rr) {
                    float v = acc[mi][ni][rg * 4 + rr] * s + bv;
                    if (RELU) v = fmaxf(v, 0.0f);
                    if (FUSE_AMAX) vmax = fmaxf(vmax, fabsf(v));
                    C[(size_t)(rowB0 + mi * 32 + rg * 8 + rr) * N + col] = v;
                }
            }
        }
    }
    if (FUSE_AMAX) {
        #pragma unroll
        for (int off = 32; off > 0; off >>= 1)
            vmax = fmaxf(vmax, __shfl_xor(vmax, off));
        if (lane == 0) smax[wid] = vmax;
        __syncthreads();
        if (tid == 0) {
            float m = smax[0];
            #pragma unroll
            for (int i = 1; i < 8; ++i) m = fmaxf(m, smax[i]);
            atomicMax(amaxOut, __float_as_uint(m));
        }
    }
#undef STG_A
#undef STG_B
#undef STG_AH
#undef STG_BH
}

// ---------- launch ----------
extern "C" void kernel_launch(void* const* d_in, const int* in_sizes, int n_in,
                              void* d_out, int out_size, void* d_ws, size_t ws_size,
                              hipStream_t stream) {
    const float* x  = (const float*)d_in[0];
    const float* w1 = (const float*)d_in[1];
    const float* b1 = (const float*)d_in[2];
    const float* w2 = (const float*)d_in[3];
    const float* b2 = (const float*)d_in[4];
    float* out = (float*)d_out;

    const int B = 4096, DIN = 4096, DH = 16384, DOUT = 4096;

    // workspace layout (packed fp4 operands)
    const size_t off_amax = 0;                                    // 4 uints
    const size_t off_Xq   = 256;                                  // 8 MB
    const size_t off_W    = off_Xq + (size_t)B * DIN / 2;         // 32 MB
    const size_t off_h    = off_W + (size_t)DIN * DH / 2;         // 256 MB f32
    const size_t off_Hq   = off_h + (size_t)B * DH * 4;           // 32 MB
    const size_t needed   = off_Hq + (size_t)B * DH / 2;

    if (ws_size < needed) {
        sentinel_kernel<<<2048, 256, 0, stream>>>(out, (long long)out_size);
        return;
    }

    char* ws = (char*)d_ws;
    unsigned* amax = (unsigned*)(ws + off_amax);  // [0]=x [1]=w1 [2]=h [3]=w2
    unsigned char* Xq = (unsigned char*)(ws + off_Xq);
    unsigned char* Wq = (unsigned char*)(ws + off_W);
    float*         h  = (float*)(ws + off_h);
    unsigned char* Hq = (unsigned char*)(ws + off_Hq);

    zero4_kernel<<<1, 64, 0, stream>>>(amax);

    absmax_kernel<<<2048, 256, 0, stream>>>(x, (long long)B * DIN, amax + 0);
    absmax_kernel<<<2048, 256, 0, stream>>>(w1, (long long)DIN * DH, amax + 1);
    absmax_kernel<<<2048, 256, 0, stream>>>(w2, (long long)DH * DOUT, amax + 3);

    quant_pack_kernel<<<2048, 256, 0, stream>>>(x, (long long)B * DIN, amax + 0,
                                                (unsigned*)Xq);
    quant_transpose_pack_kernel<<<(DIN / 64) * (DH / 64), 256, 0, stream>>>(
        w1, DIN, DH, amax + 1, Wq);

    // h = relu(Q(x) @ Q(w1) + b1), fused absmax(h) -> amax[2]
    gemm_fp4_8ph<1, 1><<<(B / 256) * (DH / 256), 512, 0, stream>>>(
        Xq, Wq, h, b1, amax + 0, amax + 1, amax + 2, B, DH, DIN);

    quant_pack_kernel<<<2048, 256, 0, stream>>>(h, (long long)B * DH, amax + 2,
                                                (unsigned*)Hq);
    quant_transpose_pack_kernel<<<(DH / 64) * (DOUT / 64), 256, 0, stream>>>(
        w2, DH, DOUT, amax + 3, Wq);

    // out = Q(h) @ Q(w2) + b2
    gemm_fp4_8ph<0, 0><<<(B / 256) * (DOUT / 256), 512, 0, stream>>>(
        Hq, Wq, out, b2, amax + 2, amax + 3, nullptr, B, DOUT, DH);
}